// Round 3
// baseline (1183.695 us; speedup 1.0000x reference)
//
#include <hip/hip_runtime.h>
#include <hip/hip_bf16.h>

// Problem constants (single-level MSDeformAttn)
#define BS     2
#define H_LVL  257
#define W_LVL  512
#define NQC    (H_LVL * W_LVL)   // 131584
#define DD     128
#define HEADS  8
#define PTS    4
#define DH     16                // DD / HEADS

constexpr int TQ = 8;            // queries per block (NQC % TQ == 0)

static __device__ __forceinline__ float b2f(__hip_bfloat16 v) { return __bfloat162float(v); }

// ---------------------------------------------------------------------------
// Kernel A: value = query @ W_value + b_value, stored bf16 as [B*HEADS][NQ][DH]
// ---------------------------------------------------------------------------
__global__ __launch_bounds__(128) void value_proj_kernel(
    const float* __restrict__ query,   // [B*NQ, 128] fp32
    const float* __restrict__ Wv,      // [128, 128] row-major fp32
    const float* __restrict__ bv,      // [128] fp32
    __hip_bfloat16* __restrict__ value)// [B*HEADS, NQ, DH] bf16
{
    __shared__ float qs[TQ][DD];
    const int t = threadIdx.x;
    const long long qbase = (long long)blockIdx.x * TQ;

    #pragma unroll
    for (int i = 0; i < TQ; ++i)
        qs[i][t] = query[(qbase + i) * DD + t];
    __syncthreads();

    float acc[TQ];
    const float bias = bv[t];
    #pragma unroll
    for (int i = 0; i < TQ; ++i) acc[i] = bias;

    for (int k = 0; k < DD; ++k) {
        const float w = Wv[k * DD + t];
        #pragma unroll
        for (int i = 0; i < TQ; ++i) acc[i] += qs[i][k] * w;
    }

    const int h = t >> 4, dh = t & 15;
    const int b = (int)(qbase / NQC);           // TQ tiles never cross batch
    #pragma unroll
    for (int i = 0; i < TQ; ++i) {
        const long long q = (qbase + i) - (long long)b * NQC;
        value[((long long)(b * HEADS + h) * NQC + q) * DH + dh] = __float2bfloat16(acc[i]);
    }
}

// ---------------------------------------------------------------------------
// Kernel B: fused offset/attn projection + softmax + bilinear sample + P·V
// writes attn_out (fp32) directly into d_out [B*NQ, 128] (col = h*16+dh)
// ---------------------------------------------------------------------------
__global__ __launch_bounds__(128) void sample_kernel(
    const float* __restrict__ query,
    const float* __restrict__ Woff,    // [128, 64] fp32
    const float* __restrict__ boff,    // [64]
    const float* __restrict__ Wattn,   // [128, 32] fp32
    const float* __restrict__ battn,   // [32]
    const __hip_bfloat16* __restrict__ value,   // [B*HEADS, NQ, DH] bf16
    float* __restrict__ attn_out)      // [B*NQ, 128] fp32 (= d_out)
{
    __shared__ float qs[TQ][DD];
    __shared__ float proj[TQ][96];             // cols 0..63 = off, 64..95 = attn
    const int t = threadIdx.x;
    const long long qbase = (long long)blockIdx.x * TQ;

    #pragma unroll
    for (int i = 0; i < TQ; ++i)
        qs[i][t] = query[(qbase + i) * DD + t];
    __syncthreads();

    // projection: TQ*96 = 768 dot products, K = 128
    for (int task = t; task < TQ * 96; task += 128) {
        const int qi = task / 96;
        const int col = task % 96;
        float acc;
        const float* wp;
        int stride;
        if (col < 64) { acc = boff[col];       wp = Woff  + col;        stride = 64; }
        else          { acc = battn[col - 64]; wp = Wattn + (col - 64); stride = 32; }
        for (int k = 0; k < DD; ++k)
            acc += qs[qi][k] * wp[k * stride];
        proj[qi][col] = acc;
    }
    __syncthreads();

    const int h = t >> 4, dh = t & 15;
    const int b = (int)(qbase / NQC);
    const __hip_bfloat16* V = value + (long long)(b * HEADS + h) * NQC * DH;

    #pragma unroll 1
    for (int i = 0; i < TQ; ++i) {
        const long long bq = qbase + i;
        const int q = (int)(bq - (long long)b * NQC);
        const int row = q >> 9;        // q / 512
        const int colq = q & 511;      // q % 512
        const float refx = (float)colq * (1.0f / 511.0f);
        const float refy = (float)row  * (1.0f / 256.0f);

        // softmax over PTS
        float a0 = proj[i][64 + h * 4 + 0];
        float a1 = proj[i][64 + h * 4 + 1];
        float a2 = proj[i][64 + h * 4 + 2];
        float a3 = proj[i][64 + h * 4 + 3];
        float m = fmaxf(fmaxf(a0, a1), fmaxf(a2, a3));
        float e0 = expf(a0 - m), e1 = expf(a1 - m), e2 = expf(a2 - m), e3 = expf(a3 - m);
        const float inv = 1.0f / (e0 + e1 + e2 + e3);
        float aw[PTS] = {e0 * inv, e1 * inv, e2 * inv, e3 * inv};

        float acc = 0.0f;
        #pragma unroll
        for (int p = 0; p < PTS; ++p) {
            const float offx = proj[i][(h * PTS + p) * 2 + 0];
            const float offy = proj[i][(h * PTS + p) * 2 + 1];
            // x = (refx + offx/W)*W - 0.5 ; y = (refy + offy/H)*H - 0.5
            const float x = refx * (float)W_LVL + offx - 0.5f;
            const float y = refy * (float)H_LVL + offy - 0.5f;
            const float x0f = floorf(x), y0f = floorf(y);
            const int x0 = (int)x0f, y0 = (int)y0f;
            const float wx1 = x - x0f, wx0 = 1.0f - wx1;
            const float wy1 = y - y0f, wy0 = 1.0f - wy1;

            float s = 0.0f;
            {
                const bool valid = (x0 >= 0) & (x0 < W_LVL) & (y0 >= 0) & (y0 < H_LVL);
                const int xc = min(max(x0, 0), W_LVL - 1), yc = min(max(y0, 0), H_LVL - 1);
                const float v = b2f(V[((long long)yc * W_LVL + xc) * DH + dh]);
                s += valid ? wx0 * wy0 * v : 0.0f;
            }
            {
                const int x1 = x0 + 1;
                const bool valid = (x1 >= 0) & (x1 < W_LVL) & (y0 >= 0) & (y0 < H_LVL);
                const int xc = min(max(x1, 0), W_LVL - 1), yc = min(max(y0, 0), H_LVL - 1);
                const float v = b2f(V[((long long)yc * W_LVL + xc) * DH + dh]);
                s += valid ? wx1 * wy0 * v : 0.0f;
            }
            {
                const int y1 = y0 + 1;
                const bool valid = (x0 >= 0) & (x0 < W_LVL) & (y1 >= 0) & (y1 < H_LVL);
                const int xc = min(max(x0, 0), W_LVL - 1), yc = min(max(y1, 0), H_LVL - 1);
                const float v = b2f(V[((long long)yc * W_LVL + xc) * DH + dh]);
                s += valid ? wx0 * wy1 * v : 0.0f;
            }
            {
                const int x1 = x0 + 1, y1 = y0 + 1;
                const bool valid = (x1 >= 0) & (x1 < W_LVL) & (y1 >= 0) & (y1 < H_LVL);
                const int xc = min(max(x1, 0), W_LVL - 1), yc = min(max(y1, 0), H_LVL - 1);
                const float v = b2f(V[((long long)yc * W_LVL + xc) * DH + dh]);
                s += valid ? wx1 * wy1 * v : 0.0f;
            }
            acc += aw[p] * s;
        }
        attn_out[bq * DD + t] = acc;
    }
}

// ---------------------------------------------------------------------------
// Kernel C: out = attn_out @ W_out + b_out + 2*query, IN PLACE on d_out (fp32).
// Safe: each block stages its own 8 rows in LDS before overwriting them;
// no cross-block row sharing.
// ---------------------------------------------------------------------------
__global__ __launch_bounds__(128) void out_proj_kernel(
    float* __restrict__ io,                  // [B*NQ, 128] fp32 (d_out)
    const float* __restrict__ Wout,          // [128, 128] fp32
    const float* __restrict__ bout,          // [128]
    const float* __restrict__ query)         // [B*NQ, 128] fp32
{
    __shared__ float as_[TQ][DD];
    const int t = threadIdx.x;
    const long long qbase = (long long)blockIdx.x * TQ;

    #pragma unroll
    for (int i = 0; i < TQ; ++i)
        as_[i][t] = io[(qbase + i) * DD + t];
    __syncthreads();

    float acc[TQ];
    const float bias = bout[t];
    #pragma unroll
    for (int i = 0; i < TQ; ++i) acc[i] = bias;

    for (int k = 0; k < DD; ++k) {
        const float w = Wout[k * DD + t];
        #pragma unroll
        for (int i = 0; i < TQ; ++i) acc[i] += as_[i][k] * w;
    }

    #pragma unroll
    for (int i = 0; i < TQ; ++i) {
        const long long idx = (qbase + i) * DD + t;
        io[idx] = acc[i] + 2.0f * query[idx];
    }
}

// ---------------------------------------------------------------------------
extern "C" void kernel_launch(void* const* d_in, const int* in_sizes, int n_in,
                              void* d_out, int out_size, void* d_ws, size_t ws_size,
                              hipStream_t stream) {
    const float* query  = (const float*)d_in[0];
    const float* Wv     = (const float*)d_in[1];
    const float* bv     = (const float*)d_in[2];
    const float* Woff   = (const float*)d_in[3];
    const float* boff   = (const float*)d_in[4];
    const float* Wattn  = (const float*)d_in[5];
    const float* battn  = (const float*)d_in[6];
    const float* Wout   = (const float*)d_in[7];
    const float* bout   = (const float*)d_in[8];
    float* out = (float*)d_out;

    // workspace: value only (67.4 MB bf16); attn staging lives in d_out
    __hip_bfloat16* value = (__hip_bfloat16*)d_ws;

    const int nblocks = BS * NQC / TQ;   // 32896
    value_proj_kernel<<<nblocks, 128, 0, stream>>>(query, Wv, bv, value);
    sample_kernel<<<nblocks, 128, 0, stream>>>(query, Woff, boff, Wattn, battn, value, out);
    out_proj_kernel<<<nblocks, 128, 0, stream>>>(out, Wout, bout, query);
}

// Round 4
// 459.888 us; speedup vs baseline: 2.5739x; 2.5739x over previous
//
#include <hip/hip_runtime.h>
#include <hip/hip_bf16.h>

// Problem constants (single-level MSDeformAttn)
#define BS     2
#define H_LVL  257
#define W_LVL  512
#define NQC    (H_LVL * W_LVL)   // 131584
#define DD     128
#define HEADS  8
#define PTS    4
#define DH     16
#define MTOT   (BS * NQC)        // 263168

typedef float v4f __attribute__((ext_vector_type(4)));
typedef short v8s __attribute__((ext_vector_type(8)));

static __device__ __forceinline__ unsigned short f2bb(float f) {
    union { float f; unsigned int u; } v; v.f = f;
    const unsigned int u = v.u;
    return (unsigned short)((u + 0x7fffu + ((u >> 16) & 1u)) >> 16);  // RNE
}
static __device__ __forceinline__ float bb2f(unsigned short h) {
    union { unsigned int u; float f; } v; v.u = ((unsigned int)h) << 16;
    return v.f;
}
static __device__ __forceinline__ void fma4(float4& acc, float w, const unsigned short* p) {
    const ushort4 r = *(const ushort4*)p;
    acc.x = fmaf(w, bb2f(r.x), acc.x);
    acc.y = fmaf(w, bb2f(r.y), acc.y);
    acc.z = fmaf(w, bb2f(r.z), acc.z);
    acc.w = fmaf(w, bb2f(r.w), acc.w);
}

// ---------------------------------------------------------------------------
// prep: transpose+convert weights to bf16 k-contiguous rows Wt[n][k], build bcat
// ---------------------------------------------------------------------------
__global__ __launch_bounds__(256) void prep_kernel(
    const float* __restrict__ Wv, const float* __restrict__ Woff,
    const float* __restrict__ Wattn, const float* __restrict__ Wout,
    const float* __restrict__ boff, const float* __restrict__ battn,
    unsigned short* __restrict__ WtV, unsigned short* __restrict__ Wt96,
    unsigned short* __restrict__ WtO, float* __restrict__ bcat)
{
    const int id = blockIdx.x * 256 + threadIdx.x;   // 0..16383 (64 blocks)
    {
        const int n = id >> 7, k = id & 127;
        WtV[id] = f2bb(Wv[k * DD + n]);
        WtO[id] = f2bb(Wout[k * DD + n]);
    }
    if (id < 96 * 128) {
        const int n = id >> 7, k = id & 127;
        Wt96[id] = f2bb(n < 64 ? Woff[k * 64 + n] : Wattn[k * 32 + (n - 64)]);
    }
    if (id < 96) bcat[id] = (id < 64) ? boff[id] : battn[id - 64];
}

// ---------------------------------------------------------------------------
// MFMA GEMM: OUT[M,NC] = A[M,128] @ W[128,NC] + bias, 64 rows/block, 4 waves.
// Wt is bf16 [NC][128] (k-contiguous). MODE 0: value-layout bf16 out.
// MODE 1: proj bf16 out [m][96]. MODE 2: fp32 in-place + b + 2*query.
// ---------------------------------------------------------------------------
template<int NT, int MODE>
__global__ __launch_bounds__(256) void gemm_kernel(
    const float* __restrict__ A,
    const unsigned short* __restrict__ Wt,
    const float* __restrict__ bias,
    unsigned short* __restrict__ dst_bf,
    float* __restrict__ dst_f,
    const float* __restrict__ query)
{
    constexpr int NC = NT * 16;
    __shared__ unsigned short As[64 * 136];   // rows padded to 136 halfwords
    __shared__ unsigned short Ws[NC * 136];
    const int t = threadIdx.x;
    const long long m0 = (long long)blockIdx.x * 64;

    // stage A: 64x128 fp32 -> bf16 (coalesced float4 reads)
    {
        const float4* src = (const float4*)(A + m0 * DD);
        #pragma unroll
        for (int rep = 0; rep < 8; ++rep) {
            const int c = rep * 256 + t;         // c = m*32 + f4
            const int m = c >> 5, f4 = c & 31;
            const float4 v = src[c];
            ushort4 hq;
            hq.x = f2bb(v.x); hq.y = f2bb(v.y); hq.z = f2bb(v.z); hq.w = f2bb(v.w);
            *(ushort4*)(&As[m * 136 + f4 * 4]) = hq;
        }
    }
    // stage W: NC x 128 bf16, flat copy into padded rows
    {
        const uint4* src = (const uint4*)Wt;     // 16B = 8 bf16
        for (int c = t; c < NC * 16; c += 256) {
            const int n = c >> 4, kc = c & 15;
            *(uint4*)(&Ws[n * 136 + kc * 8]) = src[c];
        }
    }
    __syncthreads();

    const int lane = t & 63, wave = t >> 6;
    const int l15 = lane & 15, quad = lane >> 4;

    v4f acc[NT];
    #pragma unroll
    for (int nt = 0; nt < NT; ++nt) { v4f z = {0.f, 0.f, 0.f, 0.f}; acc[nt] = z; }

    const int arow = wave * 16 + l15;            // A-frag: m = lane&15
    #pragma unroll
    for (int kk = 0; kk < 4; ++kk) {
        const v8s a = *(const v8s*)(&As[arow * 136 + kk * 32 + quad * 8]);
        #pragma unroll
        for (int nt = 0; nt < NT; ++nt) {
            const v8s b = *(const v8s*)(&Ws[(nt * 16 + l15) * 136 + kk * 32 + quad * 8]);
            acc[nt] = __builtin_amdgcn_mfma_f32_16x16x32_bf16(a, b, acc[nt], 0, 0, 0);
        }
    }

    // D layout: col n = nt*16 + l15, row m = wave*16 + quad*4 + r
    const long long mbase = m0 + wave * 16 + quad * 4;
    if (MODE == 0) {
        const int b = (int)(m0 / NQC);           // 64 | NQC, never straddles
        #pragma unroll
        for (int nt = 0; nt < NT; ++nt) {        // h = nt, dh = l15
            const float bi = bias[nt * 16 + l15];
            #pragma unroll
            for (int r = 0; r < 4; ++r) {
                const long long q = (mbase + r) - (long long)b * NQC;
                dst_bf[((long long)(b * HEADS + nt) * NQC + q) * DH + l15] =
                    f2bb(acc[nt][r] + bi);
            }
        }
    } else if (MODE == 1) {
        #pragma unroll
        for (int nt = 0; nt < NT; ++nt) {
            const float bi = bias[nt * 16 + l15];
            #pragma unroll
            for (int r = 0; r < 4; ++r)
                dst_bf[(mbase + r) * 96 + nt * 16 + l15] = f2bb(acc[nt][r] + bi);
        }
    } else {
        #pragma unroll
        for (int nt = 0; nt < NT; ++nt) {
            const float bi = bias[nt * 16 + l15];
            #pragma unroll
            for (int r = 0; r < 4; ++r) {
                const long long idx = (mbase + r) * DD + nt * 16 + l15;
                dst_f[idx] = acc[nt][r] + bi + 2.0f * query[idx];
            }
        }
    }
}

// ---------------------------------------------------------------------------
// Sampler: 256 threads = 8 queries x 32 lanes (lane = h*4 + sub).
// Phase A: proj -> LDS fp32. Phase B: per (h,p) softmax+bilinear params in
// registers. Phase C: lanes re-map to (h, dh-quarter); params via __shfl;
// ushort4 gathers; coalesced float4 store to d_out.
// ---------------------------------------------------------------------------
template<bool PRECOMP>
__global__ __launch_bounds__(256) void sample2_kernel(
    const unsigned short* __restrict__ proj,   // [M][96] bf16 (PRECOMP)
    const float* __restrict__ query,           // (!PRECOMP)
    const float* __restrict__ Woff, const float* __restrict__ boff,
    const float* __restrict__ Wattn, const float* __restrict__ battn,
    const unsigned short* __restrict__ value,  // [16][NQC][16] bf16
    float* __restrict__ attn_out)              // d_out fp32
{
    __shared__ float projF[8][96];
    const int t = threadIdx.x;
    const long long qbase = (long long)blockIdx.x * 8;

    if constexpr (PRECOMP) {
        if (t < 192) {                         // 8*96 bf16 = 192 ushort4
            const ushort4 r = *(const ushort4*)(proj + qbase * 96 + t * 4);
            const int qq = (t * 4) / 96, c = (t * 4) % 96;   // 4 | 96: no straddle
            projF[qq][c]     = bb2f(r.x);
            projF[qq][c + 1] = bb2f(r.y);
            projF[qq][c + 2] = bb2f(r.z);
            projF[qq][c + 3] = bb2f(r.w);
        }
        __syncthreads();
    } else {
        __shared__ float qs[8][DD];
        {
            const int qi = t >> 5, k4 = (t & 31) * 4;
            const float4 v = *(const float4*)(query + (qbase + qi) * DD + k4);
            qs[qi][k4] = v.x; qs[qi][k4 + 1] = v.y; qs[qi][k4 + 2] = v.z; qs[qi][k4 + 3] = v.w;
        }
        __syncthreads();
        for (int task = t; task < 768; task += 256) {
            const int qi = task / 96, c = task % 96;
            float a; const float* wp; int stride;
            if (c < 64) { a = boff[c];       wp = Woff  + c;        stride = 64; }
            else        { a = battn[c - 64]; wp = Wattn + (c - 64); stride = 32; }
            for (int k = 0; k < DD; ++k) a += qs[qi][k] * wp[k * stride];
            projF[qi][c] = a;
        }
        __syncthreads();
    }

    const int q_loc = t >> 5, lq = t & 31;
    const int h = lq >> 2, p_own = lq & 3;
    const long long bq = qbase + q_loc;        // 8 | NQC: block never straddles batch
    const int b = (int)(bq / NQC);
    const int qidx = (int)(bq - (long long)b * NQC);
    const int row = qidx >> 9, col = qidx & 511;

    // this lane's point (h, p_own): softmax weight + bilinear params
    const float offx = projF[q_loc][(h * PTS + p_own) * 2];
    const float offy = projF[q_loc][(h * PTS + p_own) * 2 + 1];
    const float al   = projF[q_loc][64 + h * PTS + p_own];
    float mx = fmaxf(al, __shfl_xor(al, 1));
    mx = fmaxf(mx, __shfl_xor(mx, 2));
    const float e = __expf(al - mx);
    float sm = e + __shfl_xor(e, 1);
    sm += __shfl_xor(sm, 2);
    const float aw = e / sm;

    const float x = (float)col * (1.0f / 511.0f) * (float)W_LVL + offx - 0.5f;
    const float y = (float)row * (1.0f / 256.0f) * (float)H_LVL + offy - 0.5f;
    const float x0f = floorf(x), y0f = floorf(y);
    const int x0 = (int)x0f, y0 = (int)y0f;
    const int x1 = x0 + 1, y1 = y0 + 1;
    const float wx1 = x - x0f, wx0 = 1.0f - wx1;
    const float wy1 = y - y0f, wy0 = 1.0f - wy1;
    const float vx0 = (x0 >= 0 && x0 < W_LVL) ? 1.f : 0.f;
    const float vx1 = (x1 >= 0 && x1 < W_LVL) ? 1.f : 0.f;
    const float vy0 = (y0 >= 0 && y0 < H_LVL) ? 1.f : 0.f;
    const float vy1 = (y1 >= 0 && y1 < H_LVL) ? 1.f : 0.f;
    float w00 = aw * wx0 * wy0 * vx0 * vy0;
    float w01 = aw * wx1 * wy0 * vx1 * vy0;
    float w10 = aw * wx0 * wy1 * vx0 * vy1;
    float w11 = aw * wx1 * wy1 * vx1 * vy1;
    const int xc0 = min(max(x0, 0), W_LVL - 1), xc1 = min(max(x1, 0), W_LVL - 1);
    const int yc0 = min(max(y0, 0), H_LVL - 1), yc1 = min(max(y1, 0), H_LVL - 1);
    int i00 = yc0 * W_LVL + xc0, i01 = yc0 * W_LVL + xc1;
    int i10 = yc1 * W_LVL + xc0, i11 = yc1 * W_LVL + xc1;

    // gather phase: this lane handles dh = p_own*4 .. p_own*4+3 of head h
    const int dq4 = p_own;
    const unsigned short* V = value + (size_t)(b * HEADS + h) * NQC * DH + dq4 * 4;
    float4 acc = {0.f, 0.f, 0.f, 0.f};
    const int lbase = (t & 63) & ~3;
    #pragma unroll
    for (int p = 0; p < 4; ++p) {
        const int src = lbase + p;
        const float W00 = __shfl(w00, src, 64), W01 = __shfl(w01, src, 64);
        const float W10 = __shfl(w10, src, 64), W11 = __shfl(w11, src, 64);
        const int   I00 = __shfl(i00, src, 64), I01 = __shfl(i01, src, 64);
        const int   I10 = __shfl(i10, src, 64), I11 = __shfl(i11, src, 64);
        fma4(acc, W00, V + (size_t)I00 * DH);
        fma4(acc, W01, V + (size_t)I01 * DH);
        fma4(acc, W10, V + (size_t)I10 * DH);
        fma4(acc, W11, V + (size_t)I11 * DH);
    }
    *(float4*)(attn_out + bq * DD + h * DH + dq4 * 4) = acc;
}

// ---------------------------------------------------------------------------
extern "C" void kernel_launch(void* const* d_in, const int* in_sizes, int n_in,
                              void* d_out, int out_size, void* d_ws, size_t ws_size,
                              hipStream_t stream) {
    const float* query = (const float*)d_in[0];
    const float* Wv    = (const float*)d_in[1];
    const float* bv    = (const float*)d_in[2];
    const float* Woff  = (const float*)d_in[3];
    const float* boff  = (const float*)d_in[4];
    const float* Wattn = (const float*)d_in[5];
    const float* battn = (const float*)d_in[6];
    const float* Wout  = (const float*)d_in[7];
    const float* bout  = (const float*)d_in[8];
    float* out = (float*)d_out;

    char* ws = (char*)d_ws;
    size_t off = 0;
    unsigned short* WtV  = (unsigned short*)(ws + off); off += 16384 * 2;
    unsigned short* Wt96 = (unsigned short*)(ws + off); off += 12288 * 2;
    unsigned short* WtO  = (unsigned short*)(ws + off); off += 16384 * 2;
    float*          bcat = (float*)(ws + off);          off += 96 * 4;
    off = (off + 255) & ~(size_t)255;
    unsigned short* value = (unsigned short*)(ws + off);
    off += (size_t)BS * HEADS * NQC * DH * 2;            // 67,371,008 B
    off = (off + 255) & ~(size_t)255;
    unsigned short* proj = (unsigned short*)(ws + off);
    const size_t proj_need = (size_t)MTOT * 96 * 2;      // 50,528,256 B
    const bool precomp = (ws_size >= off + proj_need);

    prep_kernel<<<64, 256, 0, stream>>>(Wv, Woff, Wattn, Wout, boff, battn,
                                        WtV, Wt96, WtO, bcat);
    gemm_kernel<8, 0><<<MTOT / 64, 256, 0, stream>>>(query, WtV, bv, value, nullptr, nullptr);
    if (precomp) {
        gemm_kernel<6, 1><<<MTOT / 64, 256, 0, stream>>>(query, Wt96, bcat, proj, nullptr, nullptr);
        sample2_kernel<true><<<MTOT / 8, 256, 0, stream>>>(proj, nullptr, nullptr, nullptr,
                                                           nullptr, nullptr, value, out);
    } else {
        sample2_kernel<false><<<MTOT / 8, 256, 0, stream>>>(nullptr, query, Woff, boff,
                                                            Wattn, battn, value, out);
    }
    gemm_kernel<8, 2><<<MTOT / 64, 256, 0, stream>>>(out, WtO, bout, nullptr, out, query);
}